// Round 16
// baseline (157.916 us; speedup 1.0000x reference)
//
#include <hip/hip_runtime.h>
#include <hip/hip_bf16.h>
#include <stdint.h>

// out_re[b,i] = sum_{j,l} Re{ x[b,j,l]*k[i,j]*conj(k[i,l]) },  d_out = Re only.
//   T[i,j]: T_re = P·R + Q·M ; T_im = P·M + Q·(-R)  (A = K-frags in regs, B = X
//   chunks from LDS);  out_re[b,i] = sum_j T_re*p[i,j] - T_im*q[i,j].
// Round-16: TWO independent blocks per CU. 256-thr blocks (4 waves), grid 512,
// 48KB LDS (3 x 16KB X bufs) -> 2 blocks/CU = 2 waves/SIMD from DIFFERENT
// barrier groups: block B's waves fill every stall of block A (barrier convoy,
// WAITV skew, ds_read latency chains) — the unhidden-latency binder of r12-15.
// Wave = i-quarter: K-A frags 64 VGPR + kwp[2][8] weights 64 VGPR; all 4 waves
// compute every phase; wave owns its 32 output i's -> no cross-wave reduce.
// X chunk = 16 j-rows (8 phases/batch, NBAT=4); r14-verified vmcnt ledger
// (4 DMA/stage/wave, 3 chunks in flight, WAITV(8) steady, 8/4/0 tail).

typedef __attribute__((ext_vector_type(8))) __bf16 bf16x8;
typedef __attribute__((ext_vector_type(4))) float f32x4;
typedef __attribute__((ext_vector_type(4))) unsigned int u32x4;

#define EDIM 128
#define NBAT 4
#define XBUF 16384
#define XM_OFF 8192

static __device__ inline bf16x8 neg8(bf16x8 v) {
    u32x4 u = __builtin_bit_cast(u32x4, v);
    u ^= (u32x4){0x80008000u, 0x80008000u, 0x80008000u, 0x80008000u};
    return __builtin_bit_cast(bf16x8, u);
}

#define ASG(p) (__attribute__((address_space(1))) const void*)(p)
#define ASL(p) (__attribute__((address_space(3))) void*)(p)
#define WAITV(N_) asm volatile("s_waitcnt vmcnt(" #N_ ")" ::: "memory")
#define BARRIER() asm volatile("s_barrier" ::: "memory")

__global__ __launch_bounds__(256, 2) void qmeas_kernel(
    const float* __restrict__ R, const float* __restrict__ M,
    const float* __restrict__ Kern, float* __restrict__ out, int nout)
{
    __shared__ __align__(16) unsigned char smem[3 * XBUF];   // 48KB

    const int t    = threadIdx.x;
    const int lane = t & 63;
    const int w    = t >> 6;       // wave 0..3 = i-quarter
    const int li   = lane & 15;
    const int s    = lane >> 4;    // 0..3
    const int rhi  = lane >> 5;    // 0..1
    const int key  = li & 7;       // X swizzle key on read
    const int bat0 = blockIdx.x * NBAT;

    // stage chunk q_ (j rows [16q_,16q_+16), full l) of batch base xb_ into xo_
    // 4 DMA/wave; LDS dest wave-uniform, global src per-lane pre-swizzled.
#define STAGE_X(xb_, q_, xo_)                                                   \
    do {                                                                        \
        _Pragma("unroll")                                                       \
        for (int k2 = 0; k2 < 2; ++k2) {                                        \
            int rloc = (w << 2) + (k2 << 1);                                    \
            int rowl = rloc + rhi;                                              \
            int colf = ((lane & 31) ^ (rowl & 7)) << 2;                         \
            size_t src = (xb_) + (size_t)((q_) * 16 + rowl) * EDIM + colf;      \
            unsigned char* d_ = smem + (xo_) + rloc * 512;                      \
            __builtin_amdgcn_global_load_lds(ASG(R + src), ASL(d_), 16, 0, 0);  \
            __builtin_amdgcn_global_load_lds(ASG(M + src), ASL(d_ + XM_OFF), 16, 0, 0); \
        }                                                                       \
    } while (0)

    // prologue DMA first (fly under the K/kwp register loads below)
    const size_t xb0 = (size_t)bat0 * (EDIM * EDIM);
    STAGE_X(xb0, 0, 0 * XBUF);
    STAGE_X(xb0, 1, 1 * XBUF);
    STAGE_X(xb0, 2, 2 * XBUF);

    // ---- K-A fragments in regs (64 VGPR): pa[nn][u] = K[(2w+nn)*16+li][u*32+s*8+e]
    bf16x8 pa[2][4], qa[2][4];
#pragma unroll
    for (int nn = 0; nn < 2; ++nn) {
#pragma unroll
        for (int u = 0; u < 4; ++u) {
            const int i = (w * 2 + nn) * 16 + li;
            const float* g = Kern + (((size_t)i * EDIM + u * 32 + s * 8) << 1);
            f32x4 f0 = *(const f32x4*)(g);
            f32x4 f1 = *(const f32x4*)(g + 4);
            f32x4 f2 = *(const f32x4*)(g + 8);
            f32x4 f3 = *(const f32x4*)(g + 12);
            bf16x8 pv, qv;
            pv[0] = (__bf16)f0[0]; qv[0] = (__bf16)f0[1];
            pv[1] = (__bf16)f0[2]; qv[1] = (__bf16)f0[3];
            pv[2] = (__bf16)f1[0]; qv[2] = (__bf16)f1[1];
            pv[3] = (__bf16)f1[2]; qv[3] = (__bf16)f1[3];
            pv[4] = (__bf16)f2[0]; qv[4] = (__bf16)f2[1];
            pv[5] = (__bf16)f2[2]; qv[5] = (__bf16)f2[3];
            pv[6] = (__bf16)f3[0]; qv[6] = (__bf16)f3[1];
            pv[7] = (__bf16)f3[2]; qv[7] = (__bf16)f3[3];
            pa[nn][u] = pv;
            qa[nn][u] = qv;
        }
    }

    // ---- epilogue weights in regs (64 VGPR): kwp[nn][jt][2r]=p,[2r+1]=q
    //      = k[(2w+nn)*16 + s*4 + r][jt*16 + li],  jt = 0..7 (full j)
    const float2* K2 = (const float2*)Kern;
    bf16x8 kwp[2][8];
#pragma unroll
    for (int nn = 0; nn < 2; ++nn) {
#pragma unroll
        for (int jt = 0; jt < 8; ++jt) {
#pragma unroll
            for (int r = 0; r < 4; ++r) {
                float2 kv = K2[(size_t)((w * 2 + nn) * 16 + s * 4 + r) * EDIM
                               + jt * 16 + li];
                kwp[nn][jt][2 * r]     = (__bf16)kv.x;
                kwp[nn][jt][2 * r + 1] = (__bf16)kv.y;
            }
        }
    }

    float reS[2][4] = {{0.f,0.f,0.f,0.f},{0.f,0.f,0.f,0.f}};

    // compute chunk p_ (j rows [16p_,+16)) from LDS offset xo_, fold into reS
#define COMPUTE_FOLD(p_, xo_)                                                   \
    do {                                                                        \
        const unsigned char* Xb = smem + (xo_);                                 \
        f32x4 are0 = (f32x4){0.f,0.f,0.f,0.f}, are1 = (f32x4){0.f,0.f,0.f,0.f}; \
        f32x4 aim0 = (f32x4){0.f,0.f,0.f,0.f}, aim1 = (f32x4){0.f,0.f,0.f,0.f}; \
        _Pragma("unroll")                                                       \
        for (int u = 0; u < 4; ++u) {                                           \
            int c0 = (u << 3) + (s << 1);                                       \
            int a0 = li * 512 + ((c0 ^ key) << 4);                              \
            int a1 = li * 512 + (((c0 + 1) ^ key) << 4);                        \
            f32x4 r0 = *(const f32x4*)(Xb + a0);                                \
            f32x4 r1 = *(const f32x4*)(Xb + a1);                                \
            f32x4 m0 = *(const f32x4*)(Xb + XM_OFF + a0);                       \
            f32x4 m1 = *(const f32x4*)(Xb + XM_OFF + a1);                       \
            bf16x8 xr, xm;                                                      \
            _Pragma("unroll")                                                   \
            for (int e = 0; e < 4; ++e) {                                       \
                xr[e] = (__bf16)r0[e]; xr[4 + e] = (__bf16)r1[e];               \
                xm[e] = (__bf16)m0[e]; xm[4 + e] = (__bf16)m1[e];               \
            }                                                                   \
            bf16x8 xrn = neg8(xr);                                              \
            are0 = __builtin_amdgcn_mfma_f32_16x16x32_bf16(pa[0][u], xr,  are0, 0, 0, 0); \
            are0 = __builtin_amdgcn_mfma_f32_16x16x32_bf16(qa[0][u], xm,  are0, 0, 0, 0); \
            aim0 = __builtin_amdgcn_mfma_f32_16x16x32_bf16(pa[0][u], xm,  aim0, 0, 0, 0); \
            aim0 = __builtin_amdgcn_mfma_f32_16x16x32_bf16(qa[0][u], xrn, aim0, 0, 0, 0); \
            are1 = __builtin_amdgcn_mfma_f32_16x16x32_bf16(pa[1][u], xr,  are1, 0, 0, 0); \
            are1 = __builtin_amdgcn_mfma_f32_16x16x32_bf16(qa[1][u], xm,  are1, 0, 0, 0); \
            aim1 = __builtin_amdgcn_mfma_f32_16x16x32_bf16(pa[1][u], xm,  aim1, 0, 0, 0); \
            aim1 = __builtin_amdgcn_mfma_f32_16x16x32_bf16(qa[1][u], xrn, aim1, 0, 0, 0); \
        }                                                                       \
        {                                                                       \
            const bf16x8 kv0 = kwp[0][p_];                                      \
            const bf16x8 kv1 = kwp[1][p_];                                      \
            _Pragma("unroll")                                                   \
            for (int r = 0; r < 4; ++r) {                                       \
                reS[0][r] += are0[r] * (float)kv0[2*r] - aim0[r] * (float)kv0[2*r+1]; \
                reS[1][r] += are1[r] * (float)kv1[2*r] - aim1[r] * (float)kv1[2*r+1]; \
            }                                                                   \
        }                                                                       \
    } while (0)

    int mb = 0;   // buf index of p0; advances +2 per batch (8 mod 3 = 2)

#pragma unroll 1
    for (int n = 0; n < NBAT; ++n) {
        const size_t xbn  = (size_t)(bat0 + n) * (EDIM * EDIM);
        const size_t xbn1 = xbn + (size_t)(EDIM * EDIM);
        const int o0 = mb * XBUF;
        const int o1 = (mb >= 2 ? mb - 2 : mb + 1) * XBUF;
        const int o2 = (mb >= 1 ? mb - 1 : mb + 2) * XBUF;
        const bool more = (n + 1 < NBAT);

        WAITV(8); BARRIER(); COMPUTE_FOLD(0, o0); BARRIER(); STAGE_X(xbn, 3, o0);
        WAITV(8); BARRIER(); COMPUTE_FOLD(1, o1); BARRIER(); STAGE_X(xbn, 4, o1);
        WAITV(8); BARRIER(); COMPUTE_FOLD(2, o2); BARRIER(); STAGE_X(xbn, 5, o2);
        WAITV(8); BARRIER(); COMPUTE_FOLD(3, o0); BARRIER(); STAGE_X(xbn, 6, o0);
        WAITV(8); BARRIER(); COMPUTE_FOLD(4, o1); BARRIER(); STAGE_X(xbn, 7, o1);
        WAITV(8); BARRIER(); COMPUTE_FOLD(5, o2); BARRIER();
        if (more) STAGE_X(xbn1, 0, o2);
        if (more) { WAITV(8); } else { WAITV(4); }
        BARRIER(); COMPUTE_FOLD(6, o0); BARRIER();
        if (more) STAGE_X(xbn1, 1, o0);
        if (more) { WAITV(8); } else { WAITV(0); }
        BARRIER(); COMPUTE_FOLD(7, o1);

        // batch done: reduce over li (j within chunks already folded), store
#pragma unroll
        for (int nn = 0; nn < 2; ++nn) {
#pragma unroll
            for (int r = 0; r < 4; ++r) {
                reS[nn][r] += __shfl_xor(reS[nn][r], 1);
                reS[nn][r] += __shfl_xor(reS[nn][r], 2);
                reS[nn][r] += __shfl_xor(reS[nn][r], 4);
                reS[nn][r] += __shfl_xor(reS[nn][r], 8);
            }
        }
        if (li == 0) {
#pragma unroll
            for (int nn = 0; nn < 2; ++nn) {
                int oi = (bat0 + n) * EDIM + (w * 2 + nn) * 16 + s * 4;
                if (oi + 3 < nout) {
                    f32x4 o;
                    o[0] = reS[nn][0]; o[1] = reS[nn][1];
                    o[2] = reS[nn][2]; o[3] = reS[nn][3];
                    *(f32x4*)(out + oi) = o;
                }
            }
        }
        reS[0][0]=reS[0][1]=reS[0][2]=reS[0][3]=0.f;
        reS[1][0]=reS[1][1]=reS[1][2]=reS[1][3]=0.f;

        BARRIER();
        if (more) STAGE_X(xbn1, 2, o1);

        mb += 2; if (mb >= 3) mb -= 3;
    }
}

extern "C" void kernel_launch(void* const* d_in, const int* in_sizes, int n_in,
                              void* d_out, int out_size, void* d_ws, size_t ws_size,
                              hipStream_t stream) {
    const float* R    = (const float*)d_in[0];
    const float* M    = (const float*)d_in[1];
    const float* Kern = (const float*)d_in[2];
    float*       out  = (float*)d_out;
    const int    B    = in_sizes[0] / (EDIM * EDIM);   // 2048

    int grid = B / NBAT;   // 512 -> 2 blocks/CU
    qmeas_kernel<<<grid, 256, 0, stream>>>(R, M, Kern, out, out_size);
}

// Round 17
// 56.856 us; speedup vs baseline: 2.7775x; 2.7775x over previous
//
#include <hip/hip_runtime.h>
#include <hip/hip_bf16.h>
#include <stdint.h>

// out_re[b,i] = sum_{j,l} Re{ x[b,j,l]*k[i,j]*conj(k[i,l]) },  d_out = Re only.
//   T_re = P·R + Q·M ; T_im = P·M + Q·(-R)  (A = K-frags in regs, B = X in LDS)
//   out_re[b,i] = sum_j T_re*p[i,j] - T_im*q[i,j]
// Round-17: dual-stream j-split. 512-thr block (8 waves), wave (iw=w&3,
// jh=w>>2) owns i in [32iw,+32) x j-half jh. Two chunk streams (16 j-rows
// each), 3 x 16KB bufs per stream: every phase ALL 8 waves compute (2/SIMD)
// and each chunk is read by only 4 waves (halved LDS port load vs r12 -
// combining r12's wave density with r15's traffic cut). kwp[2][4] only (32
// regs) to stay under the spill cliff that killed r16. r14-verified vmcnt
// ledger: 4 DMA/stage-event, WAITV(8) steady, 8/8/4/0 tail.

typedef __attribute__((ext_vector_type(8))) __bf16 bf16x8;
typedef __attribute__((ext_vector_type(4))) float f32x4;
typedef __attribute__((ext_vector_type(4))) unsigned int u32x4;

#define EDIM 128
#define NBAT 8
#define XBUF 16384
#define SSTR (3 * XBUF)          // stream stride (3 bufs of 16KB)
#define PART_OFF (2 * SSTR)      // 98304
#define LDS_BYTES (2 * SSTR + 512)

static __device__ inline bf16x8 neg8(bf16x8 v) {
    u32x4 u = __builtin_bit_cast(u32x4, v);
    u ^= (u32x4){0x80008000u, 0x80008000u, 0x80008000u, 0x80008000u};
    return __builtin_bit_cast(bf16x8, u);
}

#define ASG(p) (__attribute__((address_space(1))) const void*)(p)
#define ASL(p) (__attribute__((address_space(3))) void*)(p)
#define WAITV(N_) asm volatile("s_waitcnt vmcnt(" #N_ ")" ::: "memory")
#define WAITLGKM() asm volatile("s_waitcnt lgkmcnt(0)" ::: "memory")
#define BARRIER() asm volatile("s_barrier" ::: "memory")

__global__ __launch_bounds__(512, 2) void qmeas_kernel(
    const float* __restrict__ R, const float* __restrict__ M,
    const float* __restrict__ Kern, float* __restrict__ out, int nout)
{
    extern __shared__ unsigned char smem[];  // stream0 48K | stream1 48K | part

    const int t    = threadIdx.x;
    const int lane = t & 63;
    const int w    = t >> 6;       // wave 0..7
    const int li   = lane & 15;
    const int s    = lane >> 4;    // 0..3
    const int rhi  = lane >> 5;    // 0..1
    const int iw   = w & 3;        // i-block [32iw, 32iw+32)
    const int jh   = w >> 2;       // j-half (chunk stream)
    const int key  = li & 7;
    const int bat0 = blockIdx.x * NBAT;

    // ---- K-A fragments in regs (64 VGPR), loaded once (before DMA so the
    //      compiler's cvt-waits don't drain the staging queue) ----
    bf16x8 pa[2][4], qa[2][4];
#pragma unroll
    for (int nn = 0; nn < 2; ++nn) {
#pragma unroll
        for (int u = 0; u < 4; ++u) {
            const int i = (iw * 2 + nn) * 16 + li;
            const float* g = Kern + (((size_t)i * EDIM + u * 32 + s * 8) << 1);
            f32x4 f0 = *(const f32x4*)(g);
            f32x4 f1 = *(const f32x4*)(g + 4);
            f32x4 f2 = *(const f32x4*)(g + 8);
            f32x4 f3 = *(const f32x4*)(g + 12);
            bf16x8 pv, qv;
            pv[0] = (__bf16)f0[0]; qv[0] = (__bf16)f0[1];
            pv[1] = (__bf16)f0[2]; qv[1] = (__bf16)f0[3];
            pv[2] = (__bf16)f1[0]; qv[2] = (__bf16)f1[1];
            pv[3] = (__bf16)f1[2]; qv[3] = (__bf16)f1[3];
            pv[4] = (__bf16)f2[0]; qv[4] = (__bf16)f2[1];
            pv[5] = (__bf16)f2[2]; qv[5] = (__bf16)f2[3];
            pv[6] = (__bf16)f3[0]; qv[6] = (__bf16)f3[1];
            pv[7] = (__bf16)f3[2]; qv[7] = (__bf16)f3[3];
            pa[nn][u] = pv;
            qa[nn][u] = qv;
        }
    }

    // ---- epilogue weights (32 VGPR): kwp[nn][p][2r]=p, [2r+1]=q at
    //      k[(2iw+nn)*16 + s*4 + r][(jh*4+p)*16 + li] ----
    const float2* K2 = (const float2*)Kern;
    bf16x8 kwp[2][4];
#pragma unroll
    for (int nn = 0; nn < 2; ++nn) {
#pragma unroll
        for (int p = 0; p < 4; ++p) {
#pragma unroll
            for (int r = 0; r < 4; ++r) {
                float2 kv = K2[(size_t)((iw * 2 + nn) * 16 + s * 4 + r) * EDIM
                               + (jh * 4 + p) * 16 + li];
                kwp[nn][p][2 * r]     = (__bf16)kv.x;
                kwp[nn][p][2 * r + 1] = (__bf16)kv.y;
            }
        }
    }

    // stage phase p_ chunks for BOTH streams (chunk p_ -> stream0 buf o_,
    // chunk 4+p_ -> stream1 buf o_). 4 DMA issues per thread total.
    // Wave w covers rows {2w, 2w+1} of each 16-row chunk; dest linear,
    // source col pre-swizzled by (row & 7).
#define STAGE2(xb_, p_, o_)                                                     \
    do {                                                                        \
        _Pragma("unroll")                                                       \
        for (int st = 0; st < 2; ++st) {                                        \
            const int c_   = st * 4 + (p_);                                     \
            const int sb_  = st * SSTR + (o_);                                  \
            const int rowl = (w << 1) + rhi;                                    \
            const int colf = (((lane & 31) ^ (rowl & 7)) << 2);                 \
            const size_t src = (xb_) + (size_t)(c_ * 16 + rowl) * EDIM + colf;  \
            unsigned char* dR = smem + sb_ + w * 1024;                          \
            __builtin_amdgcn_global_load_lds(ASG(R + src), ASL(dR), 16, 0, 0);  \
            __builtin_amdgcn_global_load_lds(ASG(M + src), ASL(dR + 8192), 16, 0, 0); \
        }                                                                       \
    } while (0)

    // prologue: phases 0,1,2 into bufs 0,1,2 (both streams)
    const size_t xb0 = (size_t)bat0 * (EDIM * EDIM);
    STAGE2(xb0, 0, 0 * XBUF);
    STAGE2(xb0, 1, 1 * XBUF);
    STAGE2(xb0, 2, 2 * XBUF);

    float reS[2][4] = {{0.f,0.f,0.f,0.f},{0.f,0.f,0.f,0.f}};
    float* part = (float*)(smem + PART_OFF);

    // compute this wave's chunk of phase p_ from its stream's buf o_
#define COMPUTE_FOLD(p_, o_)                                                    \
    do {                                                                        \
        const unsigned char* Xb = smem + (jh ? SSTR : 0) + (o_);                \
        f32x4 are0 = (f32x4){0.f,0.f,0.f,0.f}, are1 = (f32x4){0.f,0.f,0.f,0.f}; \
        f32x4 aim0 = (f32x4){0.f,0.f,0.f,0.f}, aim1 = (f32x4){0.f,0.f,0.f,0.f}; \
        _Pragma("unroll")                                                       \
        for (int u = 0; u < 4; ++u) {                                           \
            int c0 = (u << 3) + (s << 1);                                       \
            int a0 = li * 512 + ((c0 ^ key) << 4);                              \
            int a1 = li * 512 + (((c0 + 1) ^ key) << 4);                        \
            f32x4 r0 = *(const f32x4*)(Xb + a0);                                \
            f32x4 r1 = *(const f32x4*)(Xb + a1);                                \
            f32x4 m0 = *(const f32x4*)(Xb + 8192 + a0);                         \
            f32x4 m1 = *(const f32x4*)(Xb + 8192 + a1);                         \
            bf16x8 xr, xm;                                                      \
            _Pragma("unroll")                                                   \
            for (int e = 0; e < 4; ++e) {                                       \
                xr[e] = (__bf16)r0[e]; xr[4 + e] = (__bf16)r1[e];               \
                xm[e] = (__bf16)m0[e]; xm[4 + e] = (__bf16)m1[e];               \
            }                                                                   \
            bf16x8 xrn = neg8(xr);                                              \
            are0 = __builtin_amdgcn_mfma_f32_16x16x32_bf16(pa[0][u], xr,  are0, 0, 0, 0); \
            are0 = __builtin_amdgcn_mfma_f32_16x16x32_bf16(qa[0][u], xm,  are0, 0, 0, 0); \
            aim0 = __builtin_amdgcn_mfma_f32_16x16x32_bf16(pa[0][u], xm,  aim0, 0, 0, 0); \
            aim0 = __builtin_amdgcn_mfma_f32_16x16x32_bf16(qa[0][u], xrn, aim0, 0, 0, 0); \
            are1 = __builtin_amdgcn_mfma_f32_16x16x32_bf16(pa[1][u], xr,  are1, 0, 0, 0); \
            are1 = __builtin_amdgcn_mfma_f32_16x16x32_bf16(qa[1][u], xm,  are1, 0, 0, 0); \
            aim1 = __builtin_amdgcn_mfma_f32_16x16x32_bf16(pa[1][u], xm,  aim1, 0, 0, 0); \
            aim1 = __builtin_amdgcn_mfma_f32_16x16x32_bf16(qa[1][u], xrn, aim1, 0, 0, 0); \
        }                                                                       \
        {                                                                       \
            const bf16x8 kv0 = kwp[0][p_];                                      \
            const bf16x8 kv1 = kwp[1][p_];                                      \
            _Pragma("unroll")                                                   \
            for (int r = 0; r < 4; ++r) {                                       \
                reS[0][r] += are0[r] * (float)kv0[2*r] - aim0[r] * (float)kv0[2*r+1]; \
                reS[1][r] += are1[r] * (float)kv1[2*r] - aim1[r] * (float)kv1[2*r+1]; \
            }                                                                   \
        }                                                                       \
    } while (0)

    int m0i = 0, m1i = 1, m2i = 2;   // buf rotation +1/batch (4 mod 3 = 1)

#pragma unroll 1
    for (int n = 0; n < NBAT; ++n) {
        const size_t xbn  = (size_t)(bat0 + n) * (EDIM * EDIM);
        const size_t xbn1 = xbn + (size_t)(EDIM * EDIM);
        const int xo0 = m0i * XBUF;
        const int xo1 = m1i * XBUF;
        const int xo2 = m2i * XBUF;
        const bool more = (n + 1 < NBAT);

        // p0
        WAITV(8); BARRIER();
        COMPUTE_FOLD(0, xo0);
        BARRIER();
        STAGE2(xbn, 3, xo0);
        // p1
        WAITV(8); BARRIER();
        COMPUTE_FOLD(1, xo1);
        BARRIER();
        if (more) STAGE2(xbn1, 0, xo1);
        // p2
        if (more) { WAITV(8); } else { WAITV(4); }
        BARRIER();
        COMPUTE_FOLD(2, xo2);
        BARRIER();
        if (more) STAGE2(xbn1, 1, xo2);
        // p3: compute, cross-jh combine, store
        if (more) { WAITV(8); } else { WAITV(0); }
        BARRIER();
        COMPUTE_FOLD(3, xo0);
#pragma unroll
        for (int nn = 0; nn < 2; ++nn) {
#pragma unroll
            for (int r = 0; r < 4; ++r) {
                reS[nn][r] += __shfl_xor(reS[nn][r], 1);
                reS[nn][r] += __shfl_xor(reS[nn][r], 2);
                reS[nn][r] += __shfl_xor(reS[nn][r], 4);
                reS[nn][r] += __shfl_xor(reS[nn][r], 8);
            }
        }
        if (jh == 0 && li == 0) {
#pragma unroll
            for (int nn = 0; nn < 2; ++nn) {
                f32x4 o;
                o[0] = reS[nn][0]; o[1] = reS[nn][1];
                o[2] = reS[nn][2]; o[3] = reS[nn][3];
                *(f32x4*)(part + (iw * 2 + nn) * 16 + s * 4) = o;
            }
        }
        WAITLGKM();
        BARRIER();                       // part visible + bufs consumed (WAR)
        if (jh == 1 && li == 0) {
#pragma unroll
            for (int nn = 0; nn < 2; ++nn) {
                f32x4 pv = *(const f32x4*)(part + (iw * 2 + nn) * 16 + s * 4);
                int oi = (bat0 + n) * EDIM + (iw * 2 + nn) * 16 + s * 4;
                if (oi + 3 < nout) {
                    f32x4 o;
                    o[0] = reS[nn][0] + pv[0];
                    o[1] = reS[nn][1] + pv[1];
                    o[2] = reS[nn][2] + pv[2];
                    o[3] = reS[nn][3] + pv[3];
                    *(f32x4*)(out + oi) = o;
                }
            }
        }
        reS[0][0]=reS[0][1]=reS[0][2]=reS[0][3]=0.f;
        reS[1][0]=reS[1][1]=reS[1][2]=reS[1][3]=0.f;
        if (more) STAGE2(xbn1, 2, xo0);

        int tmp = m0i; m0i = m1i; m1i = m2i; m2i = tmp;
    }
}

extern "C" void kernel_launch(void* const* d_in, const int* in_sizes, int n_in,
                              void* d_out, int out_size, void* d_ws, size_t ws_size,
                              hipStream_t stream) {
    const float* R    = (const float*)d_in[0];
    const float* M    = (const float*)d_in[1];
    const float* Kern = (const float*)d_in[2];
    float*       out  = (float*)d_out;
    const int    B    = in_sizes[0] / (EDIM * EDIM);   // 2048

    hipFuncSetAttribute((const void*)qmeas_kernel,
                        hipFuncAttributeMaxDynamicSharedMemorySize, LDS_BYTES);

    int grid = B / NBAT;   // 256
    qmeas_kernel<<<grid, 512, LDS_BYTES, stream>>>(R, M, Kern, out, out_size);
}

// Round 18
// 56.812 us; speedup vs baseline: 2.7796x; 1.0008x over previous
//
#include <hip/hip_runtime.h>
#include <hip/hip_bf16.h>
#include <stdint.h>

// out_re[b,i] = sum_{j,l} Re{ x[b,j,l]*k[i,j]*conj(k[i,l]) },  d_out = Re only.
//   T_re = P·R + Q·M ; T_im = P·M + Q·(-R)  (A = K-frags in regs, B = X in LDS)
//   out_re[b,i] = sum_j T_re*p[i,j] - T_im*q[i,j]
// Round-18: r17 dual-stream j-split + 4 bufs/stream -> ONE barrier per phase.
// Phase p: WAITV(8) -> s_barrier -> compute buf[p] -> stage (p+3)%4. The WAR
// barrier is implied: stage target buf was consumed at phase p-1, separated by
// this phase's barrier. 4 phases/batch = 0 mod 4 -> static buffer indices.
// Barriers/batch: 9 -> 5. LDS = 2*4*16KB + 512 = 128.5KB (1 block/CU as r17).
// Ledger (incl. p3 stores): steady WAITV(8) over-drains <=2 landed ops; tail
// 8/4/0. All other machinery r17-verified.

typedef __attribute__((ext_vector_type(8))) __bf16 bf16x8;
typedef __attribute__((ext_vector_type(4))) float f32x4;
typedef __attribute__((ext_vector_type(4))) unsigned int u32x4;

#define EDIM 128
#define NBAT 8
#define XBUF 16384
#define SSTR (4 * XBUF)          // stream stride (4 bufs of 16KB)
#define PART_OFF (2 * SSTR)      // 131072
#define LDS_BYTES (2 * SSTR + 512)

static __device__ inline bf16x8 neg8(bf16x8 v) {
    u32x4 u = __builtin_bit_cast(u32x4, v);
    u ^= (u32x4){0x80008000u, 0x80008000u, 0x80008000u, 0x80008000u};
    return __builtin_bit_cast(bf16x8, u);
}

#define ASG(p) (__attribute__((address_space(1))) const void*)(p)
#define ASL(p) (__attribute__((address_space(3))) void*)(p)
#define WAITV(N_) asm volatile("s_waitcnt vmcnt(" #N_ ")" ::: "memory")
#define WAITLGKM() asm volatile("s_waitcnt lgkmcnt(0)" ::: "memory")
#define BARRIER() asm volatile("s_barrier" ::: "memory")

__global__ __launch_bounds__(512, 2) void qmeas_kernel(
    const float* __restrict__ R, const float* __restrict__ M,
    const float* __restrict__ Kern, float* __restrict__ out, int nout)
{
    extern __shared__ unsigned char smem[];  // stream0 64K | stream1 64K | part

    const int t    = threadIdx.x;
    const int lane = t & 63;
    const int w    = t >> 6;       // wave 0..7
    const int li   = lane & 15;
    const int s    = lane >> 4;    // 0..3
    const int rhi  = lane >> 5;    // 0..1
    const int iw   = w & 3;        // i-block [32iw, 32iw+32)
    const int jh   = w >> 2;       // j-half (chunk stream)
    const int key  = li & 7;
    const int bat0 = blockIdx.x * NBAT;

    // ---- K-A fragments in regs (64 VGPR), loaded once ----
    bf16x8 pa[2][4], qa[2][4];
#pragma unroll
    for (int nn = 0; nn < 2; ++nn) {
#pragma unroll
        for (int u = 0; u < 4; ++u) {
            const int i = (iw * 2 + nn) * 16 + li;
            const float* g = Kern + (((size_t)i * EDIM + u * 32 + s * 8) << 1);
            f32x4 f0 = *(const f32x4*)(g);
            f32x4 f1 = *(const f32x4*)(g + 4);
            f32x4 f2 = *(const f32x4*)(g + 8);
            f32x4 f3 = *(const f32x4*)(g + 12);
            bf16x8 pv, qv;
            pv[0] = (__bf16)f0[0]; qv[0] = (__bf16)f0[1];
            pv[1] = (__bf16)f0[2]; qv[1] = (__bf16)f0[3];
            pv[2] = (__bf16)f1[0]; qv[2] = (__bf16)f1[1];
            pv[3] = (__bf16)f1[2]; qv[3] = (__bf16)f1[3];
            pv[4] = (__bf16)f2[0]; qv[4] = (__bf16)f2[1];
            pv[5] = (__bf16)f2[2]; qv[5] = (__bf16)f2[3];
            pv[6] = (__bf16)f3[0]; qv[6] = (__bf16)f3[1];
            pv[7] = (__bf16)f3[2]; qv[7] = (__bf16)f3[3];
            pa[nn][u] = pv;
            qa[nn][u] = qv;
        }
    }

    // ---- epilogue weights (32 VGPR): kwp[nn][p] at
    //      k[(2iw+nn)*16 + s*4 + r][(jh*4+p)*16 + li] ----
    const float2* K2 = (const float2*)Kern;
    bf16x8 kwp[2][4];
#pragma unroll
    for (int nn = 0; nn < 2; ++nn) {
#pragma unroll
        for (int p = 0; p < 4; ++p) {
#pragma unroll
            for (int r = 0; r < 4; ++r) {
                float2 kv = K2[(size_t)((iw * 2 + nn) * 16 + s * 4 + r) * EDIM
                               + (jh * 4 + p) * 16 + li];
                kwp[nn][p][2 * r]     = (__bf16)kv.x;
                kwp[nn][p][2 * r + 1] = (__bf16)kv.y;
            }
        }
    }

    // stage phase p_ chunks for BOTH streams into buf o_ (4 DMA/thread)
#define STAGE2(xb_, p_, o_)                                                     \
    do {                                                                        \
        _Pragma("unroll")                                                       \
        for (int st = 0; st < 2; ++st) {                                        \
            const int c_   = st * 4 + (p_);                                     \
            const int sb_  = st * SSTR + (o_);                                  \
            const int rowl = (w << 1) + rhi;                                    \
            const int colf = (((lane & 31) ^ (rowl & 7)) << 2);                 \
            const size_t src = (xb_) + (size_t)(c_ * 16 + rowl) * EDIM + colf;  \
            unsigned char* dR = smem + sb_ + w * 1024;                          \
            __builtin_amdgcn_global_load_lds(ASG(R + src), ASL(dR), 16, 0, 0);  \
            __builtin_amdgcn_global_load_lds(ASG(M + src), ASL(dR + 8192), 16, 0, 0); \
        }                                                                       \
    } while (0)

    // prologue: phases 0,1,2 into bufs 0,1,2 (both streams)
    const size_t xb0 = (size_t)bat0 * (EDIM * EDIM);
    STAGE2(xb0, 0, 0 * XBUF);
    STAGE2(xb0, 1, 1 * XBUF);
    STAGE2(xb0, 2, 2 * XBUF);

    float reS[2][4] = {{0.f,0.f,0.f,0.f},{0.f,0.f,0.f,0.f}};
    float* part = (float*)(smem + PART_OFF);

    // compute this wave's chunk of phase p_ from its stream's buf o_
#define COMPUTE_FOLD(p_, o_)                                                    \
    do {                                                                        \
        const unsigned char* Xb = smem + (jh ? SSTR : 0) + (o_);                \
        f32x4 are0 = (f32x4){0.f,0.f,0.f,0.f}, are1 = (f32x4){0.f,0.f,0.f,0.f}; \
        f32x4 aim0 = (f32x4){0.f,0.f,0.f,0.f}, aim1 = (f32x4){0.f,0.f,0.f,0.f}; \
        _Pragma("unroll")                                                       \
        for (int u = 0; u < 4; ++u) {                                           \
            int c0 = (u << 3) + (s << 1);                                       \
            int a0 = li * 512 + ((c0 ^ key) << 4);                              \
            int a1 = li * 512 + (((c0 + 1) ^ key) << 4);                        \
            f32x4 r0 = *(const f32x4*)(Xb + a0);                                \
            f32x4 r1 = *(const f32x4*)(Xb + a1);                                \
            f32x4 m0 = *(const f32x4*)(Xb + 8192 + a0);                         \
            f32x4 m1 = *(const f32x4*)(Xb + 8192 + a1);                         \
            bf16x8 xr, xm;                                                      \
            _Pragma("unroll")                                                   \
            for (int e = 0; e < 4; ++e) {                                       \
                xr[e] = (__bf16)r0[e]; xr[4 + e] = (__bf16)r1[e];               \
                xm[e] = (__bf16)m0[e]; xm[4 + e] = (__bf16)m1[e];               \
            }                                                                   \
            bf16x8 xrn = neg8(xr);                                              \
            are0 = __builtin_amdgcn_mfma_f32_16x16x32_bf16(pa[0][u], xr,  are0, 0, 0, 0); \
            are0 = __builtin_amdgcn_mfma_f32_16x16x32_bf16(qa[0][u], xm,  are0, 0, 0, 0); \
            aim0 = __builtin_amdgcn_mfma_f32_16x16x32_bf16(pa[0][u], xm,  aim0, 0, 0, 0); \
            aim0 = __builtin_amdgcn_mfma_f32_16x16x32_bf16(qa[0][u], xrn, aim0, 0, 0, 0); \
            are1 = __builtin_amdgcn_mfma_f32_16x16x32_bf16(pa[1][u], xr,  are1, 0, 0, 0); \
            are1 = __builtin_amdgcn_mfma_f32_16x16x32_bf16(qa[1][u], xm,  are1, 0, 0, 0); \
            aim1 = __builtin_amdgcn_mfma_f32_16x16x32_bf16(pa[1][u], xm,  aim1, 0, 0, 0); \
            aim1 = __builtin_amdgcn_mfma_f32_16x16x32_bf16(qa[1][u], xrn, aim1, 0, 0, 0); \
        }                                                                       \
        {                                                                       \
            const bf16x8 kv0 = kwp[0][p_];                                      \
            const bf16x8 kv1 = kwp[1][p_];                                      \
            _Pragma("unroll")                                                   \
            for (int r = 0; r < 4; ++r) {                                       \
                reS[0][r] += are0[r] * (float)kv0[2*r] - aim0[r] * (float)kv0[2*r+1]; \
                reS[1][r] += are1[r] * (float)kv1[2*r] - aim1[r] * (float)kv1[2*r+1]; \
            }                                                                   \
        }                                                                       \
    } while (0)

#pragma unroll 1
    for (int n = 0; n < NBAT; ++n) {
        const size_t xbn  = (size_t)(bat0 + n) * (EDIM * EDIM);
        const size_t xbn1 = xbn + (size_t)(EDIM * EDIM);
        const bool more = (n + 1 < NBAT);

        // p0: compute buf0; stage (n,q3) -> buf3 (consumed last batch p3)
        WAITV(8); BARRIER();
        COMPUTE_FOLD(0, 0 * XBUF);
        STAGE2(xbn, 3, 3 * XBUF);

        // p1: compute buf1; stage (n+1,q0) -> buf0 (consumed at p0 above)
        WAITV(8); BARRIER();
        COMPUTE_FOLD(1, 1 * XBUF);
        if (more) STAGE2(xbn1, 0, 0 * XBUF);

        // p2: compute buf2; stage (n+1,q1) -> buf1
        if (more) { WAITV(8); } else { WAITV(4); }
        BARRIER();
        COMPUTE_FOLD(2, 2 * XBUF);
        if (more) STAGE2(xbn1, 1, 1 * XBUF);

        // p3: compute buf3; combine + store; stage (n+1,q2) -> buf2
        if (more) { WAITV(8); } else { WAITV(0); }
        BARRIER();
        COMPUTE_FOLD(3, 3 * XBUF);
#pragma unroll
        for (int nn = 0; nn < 2; ++nn) {
#pragma unroll
            for (int r = 0; r < 4; ++r) {
                reS[nn][r] += __shfl_xor(reS[nn][r], 1);
                reS[nn][r] += __shfl_xor(reS[nn][r], 2);
                reS[nn][r] += __shfl_xor(reS[nn][r], 4);
                reS[nn][r] += __shfl_xor(reS[nn][r], 8);
            }
        }
        if (jh == 0 && li == 0) {
#pragma unroll
            for (int nn = 0; nn < 2; ++nn) {
                f32x4 o;
                o[0] = reS[nn][0]; o[1] = reS[nn][1];
                o[2] = reS[nn][2]; o[3] = reS[nn][3];
                *(f32x4*)(part + (iw * 2 + nn) * 16 + s * 4) = o;
            }
        }
        WAITLGKM();
        BARRIER();                       // part visible to jh1
        if (jh == 1 && li == 0) {
#pragma unroll
            for (int nn = 0; nn < 2; ++nn) {
                f32x4 pv = *(const f32x4*)(part + (iw * 2 + nn) * 16 + s * 4);
                int oi = (bat0 + n) * EDIM + (iw * 2 + nn) * 16 + s * 4;
                if (oi + 3 < nout) {
                    f32x4 o;
                    o[0] = reS[nn][0] + pv[0];
                    o[1] = reS[nn][1] + pv[1];
                    o[2] = reS[nn][2] + pv[2];
                    o[3] = reS[nn][3] + pv[3];
                    *(f32x4*)(out + oi) = o;
                }
            }
        }
        reS[0][0]=reS[0][1]=reS[0][2]=reS[0][3]=0.f;
        reS[1][0]=reS[1][1]=reS[1][2]=reS[1][3]=0.f;
        if (more) STAGE2(xbn1, 2, 2 * XBUF);
    }
}

extern "C" void kernel_launch(void* const* d_in, const int* in_sizes, int n_in,
                              void* d_out, int out_size, void* d_ws, size_t ws_size,
                              hipStream_t stream) {
    const float* R    = (const float*)d_in[0];
    const float* M    = (const float*)d_in[1];
    const float* Kern = (const float*)d_in[2];
    float*       out  = (float*)d_out;
    const int    B    = in_sizes[0] / (EDIM * EDIM);   // 2048

    hipFuncSetAttribute((const void*)qmeas_kernel,
                        hipFuncAttributeMaxDynamicSharedMemorySize, LDS_BYTES);

    int grid = B / NBAT;   // 256
    qmeas_kernel<<<grid, 512, LDS_BYTES, stream>>>(R, M, Kern, out, out_size);
}